// Round 8
// baseline (115.679 us; speedup 1.0000x reference)
//
#include <hip/hip_runtime.h>

// ROIPatchExtractor: B=32, C=3, H=W=448, 2x2 patches -> N=128 samples.
// Composed separable bilinear (patch->448 upsample, then ROI crop+resize):
// each output row/col = weighted 3-tap sum of <=3 consecutive patch rows/cols.
//
// r8 = r7 structure (col-per-thread, ROWS=8, channel-pipelined LDS dbuf,
// 4 barriers) + FUSED-TAP GATHER: the 3 column taps c0,c0+1,c0+2 (clamped)
// become ONE global_load_dwordx4 at base=min(ca,220) with the clamp folded
// into a 4-weight vector (exact same arithmetic). 3x fewer gather
// instructions on the suspected TA/L1-issue bottleneck (r3/r4's regression
// was this same bottleneck made 4x worse by wider per-wave spans).

#define IMG 448
#define PATCH 224
#define ROWS 8     // output rows per block; grid.x = 448/8 = 56
#define MAXPR 8    // patch-row footprint for 8 output rows: a0 span<=4, +3 taps

__device__ inline float4 make_entry(int t, int crop, int off) {
    // stage 2: output coord t -> up-image coords u0,u1 with weight wy
    float cf = (float)crop;
    float s = ((float)t + 0.5f) * cf / 448.0f - 0.5f;
    s = fminf(fmaxf(s, 0.0f), cf - 1.0f);
    int i0 = (int)s;                 // s >= 0, trunc == floor
    int i1 = min(i0 + 1, crop - 1);
    float wy = s - (float)i0;
    int u0 = off + i0;
    int u1 = off + i1;
    // stage 1: up coord u -> patch coord: s1 = 0.5*u - 0.25, clamp [0,223]
    float t0 = fminf(fmaxf(0.5f * (float)u0 - 0.25f, 0.0f), 223.0f);
    int a0 = (int)t0;
    int a1 = min(a0 + 1, 223);
    float f0 = t0 - (float)a0;
    float t1 = fminf(fmaxf(0.5f * (float)u1 - 0.25f, 0.0f), 223.0f);
    int b0 = (int)t1;
    int b1 = min(b0 + 1, 223);
    float f1 = t1 - (float)b0;
    // fold 4 taps into 3 slots relative to a0 (footprint <= a0+2)
    float g0 = (1.0f - wy) * (1.0f - f0);
    float g1 = (1.0f - wy) * f0;
    float g2 = wy * (1.0f - f1);
    float g3 = wy * f1;
    float w0 = g0, w1 = 0.0f, w2 = 0.0f;
    if (a1 == a0) w0 += g1; else w1 += g1;
    if (b0 == a0) w0 += g2; else w1 += g2;
    int ob1 = b1 - a0;
    if (ob1 == 0) w0 += g3; else if (ob1 == 1) w1 += g3; else w2 += g3;
    float4 e;
    e.x = w0; e.y = w1; e.z = w2;
    e.w = __int_as_float(a0);        // patch-local base index [0,223]
    return e;
}

__global__ __launch_bounds__(448)
void roi_patch_kernel(const float* __restrict__ x,
                      const int* __restrict__ tops,
                      const int* __restrict__ lefts,
                      const int* __restrict__ crop_hs,
                      const int* __restrict__ crop_ws,
                      float* __restrict__ out,
                      int out_size) {
    __shared__ float  hA[MAXPR][IMG];
    __shared__ float  hB[MAXPR][IMG];
    __shared__ float4 rowE[ROWS];

    const int n   = blockIdx.y;
    const int y0  = blockIdx.x * ROWS;
    const int tid = threadIdx.x;
    const int b   = n >> 2;
    const int gi  = (n >> 1) & 1;
    const int gj  = n & 1;

    const int ch = crop_hs[n], cw = crop_ws[n];
    const int tp = tops[n],    lf = lefts[n];

    // per-thread column entry (col = tid): fold 3 clamped taps into a
    // 4-weight vector over cols base..base+3 (base <= 220, never OOB)
    const float4 e = make_entry(tid, cw, lf);
    const int ca   = __float_as_int(e.w);
    const int base = min(ca, 220);
    const int s0 = ca - base;                  // 0..3
    const int s1 = min(ca + 1, 223) - base;    // 0..3
    const int s2 = min(ca + 2, 223) - base;    // 0..3
    const float Wx = (s0 == 0 ? e.x : 0.f) + (s1 == 0 ? e.y : 0.f) + (s2 == 0 ? e.z : 0.f);
    const float Wy = (s0 == 1 ? e.x : 0.f) + (s1 == 1 ? e.y : 0.f) + (s2 == 1 ? e.z : 0.f);
    const float Wz = (s0 == 2 ? e.x : 0.f) + (s1 == 2 ? e.y : 0.f) + (s2 == 2 ? e.z : 0.f);
    const float Ww = (s0 == 3 ? e.x : 0.f) + (s1 == 3 ? e.y : 0.f) + (s2 == 3 ? e.z : 0.f);
    const int cbase = gj * PATCH + base;       // global col of the 16B window

    if (tid < ROWS) rowE[tid] = make_entry(y0 + tid, ch, tp);

    // patch_indices tail (float values; harness reads flat buffer as f32)
    if (blockIdx.x == 0 && n == 0 && tid < 128) {
        out[(size_t)out_size - 128 + tid] = (float)(tid & 3);
    }
    __syncthreads();

    const int pr_min = __float_as_int(rowE[0].w);
    const int pr_max = min(__float_as_int(rowE[ROWS - 1].w) + 2, 223);
    const int nrows  = pr_max - pr_min + 1;   // <= MAXPR

    const float* xb = x + (size_t)b * 3 * IMG * IMG + (size_t)(gi * PATCH + pr_min) * IMG;
    float* ob = out + (size_t)n * 3 * IMG * IMG + (size_t)y0 * IMG + tid;

    float4 g[MAXPR];

    // ---- macro helpers (unrolled, static reg indexing) ----
#define GATHER(CH)                                                        \
    {                                                                     \
        const float* xc = xb + (size_t)(CH) * IMG * IMG + cbase;          \
        _Pragma("unroll")                                                 \
        for (int k = 0; k < MAXPR; ++k) {                                 \
            if (k < nrows) {                                              \
                g[k] = *reinterpret_cast<const float4*>(xc + (size_t)k * IMG); \
            }                                                             \
        }                                                                 \
    }

#define HWRITE(BUF)                                                       \
    {                                                                     \
        _Pragma("unroll")                                                 \
        for (int k = 0; k < MAXPR; ++k) {                                 \
            if (k < nrows) {                                              \
                BUF[k][tid] = Wx * g[k].x + Wy * g[k].y                   \
                            + Wz * g[k].z + Ww * g[k].w;                  \
            }                                                             \
        }                                                                 \
    }

#define VPASS(BUF, CH)                                                    \
    {                                                                     \
        float* orow = ob + (size_t)(CH) * IMG * IMG;                      \
        _Pragma("unroll")                                                 \
        for (int r = 0; r < ROWS; ++r) {                                  \
            const float4 re = rowE[r];                                    \
            const int ra = __float_as_int(re.w);                          \
            const int k0 = ra - pr_min;                                   \
            const int k1 = min(ra + 1, 223) - pr_min;                     \
            const int k2 = min(ra + 2, 223) - pr_min;                     \
            *orow = re.x * BUF[k0][tid] + re.y * BUF[k1][tid]             \
                  + re.z * BUF[k2][tid];                                  \
            orow += IMG;                                                  \
        }                                                                 \
    }

    // prologue: channel 0 -> hA
    GATHER(0);
    HWRITE(hA);
    __syncthreads();

    // phase 1: gather ch1 (loads in flight) || vpass ch0 ; then write hB
    GATHER(1);
    VPASS(hA, 0);
    HWRITE(hB);
    __syncthreads();

    // phase 2: gather ch2 || vpass ch1 ; then write hA
    GATHER(2);
    VPASS(hB, 1);
    HWRITE(hA);
    __syncthreads();

    // epilogue: vpass ch2
    VPASS(hA, 2);

#undef GATHER
#undef HWRITE
#undef VPASS
}

extern "C" void kernel_launch(void* const* d_in, const int* in_sizes, int n_in,
                              void* d_out, int out_size, void* d_ws, size_t ws_size,
                              hipStream_t stream) {
    const float* x        = (const float*)d_in[0];
    const int*   tops     = (const int*)d_in[1];
    const int*   lefts    = (const int*)d_in[2];
    const int*   crop_hs  = (const int*)d_in[3];
    const int*   crop_ws  = (const int*)d_in[4];
    float*       out      = (float*)d_out;

    dim3 grid(IMG / ROWS, 128);   // 56 x 128 blocks
    dim3 block(IMG);              // 448 threads = 7 waves
    roi_patch_kernel<<<grid, block, 0, stream>>>(x, tops, lefts, crop_hs, crop_ws,
                                                 out, out_size);
}

// Round 9
// 105.905 us; speedup vs baseline: 1.0923x; 1.0923x over previous
//
#include <hip/hip_runtime.h>

// ROIPatchExtractor: B=32, C=3, H=W=448, 2x2 patches -> N=128 samples.
// Composed separable bilinear (patch->448 upsample, then ROI crop+resize):
// each output row/col = weighted 3-tap sum of <=3 consecutive patch rows/cols.
//
// r9 = r7 data path (col-per-thread scalar gathers, ROWS=8, channel-pipelined
// LDS double-buffer) + SOFT BARRIERS: __syncthreads() compiles to
// "s_waitcnt vmcnt(0) lgkmcnt(0); s_barrier", which drains the previous
// vpass's 24 output stores at every phase boundary (T4 lesson: never drain
// vmcnt to 0 at interior barriers). Replace with lgkmcnt(0)-only + raw
// s_barrier: LDS ordering preserved, stores stream freely across phases.
// rowE's init barrier is folded into the prologue barrier by computing
// pr_min/pr_max per-thread.

#define IMG 448
#define PATCH 224
#define ROWS 8     // output rows per block; grid.x = 448/8 = 56
#define MAXPR 8    // patch-row footprint for 8 output rows: a0 span<=4, +3 taps

// LDS-only barrier: order DS ops, do NOT drain vector-memory (stores/gathers).
#define SOFT_BARRIER()                                          \
    do {                                                        \
        asm volatile("s_waitcnt lgkmcnt(0)" ::: "memory");      \
        __builtin_amdgcn_s_barrier();                           \
        asm volatile("" ::: "memory");                          \
    } while (0)

__device__ inline float4 make_entry(int t, int crop, int off) {
    // stage 2: output coord t -> up-image coords u0,u1 with weight wy
    float cf = (float)crop;
    float s = ((float)t + 0.5f) * cf / 448.0f - 0.5f;
    s = fminf(fmaxf(s, 0.0f), cf - 1.0f);
    int i0 = (int)s;                 // s >= 0, trunc == floor
    int i1 = min(i0 + 1, crop - 1);
    float wy = s - (float)i0;
    int u0 = off + i0;
    int u1 = off + i1;
    // stage 1: up coord u -> patch coord: s1 = 0.5*u - 0.25, clamp [0,223]
    float t0 = fminf(fmaxf(0.5f * (float)u0 - 0.25f, 0.0f), 223.0f);
    int a0 = (int)t0;
    int a1 = min(a0 + 1, 223);
    float f0 = t0 - (float)a0;
    float t1 = fminf(fmaxf(0.5f * (float)u1 - 0.25f, 0.0f), 223.0f);
    int b0 = (int)t1;
    int b1 = min(b0 + 1, 223);
    float f1 = t1 - (float)b0;
    // fold 4 taps into 3 slots relative to a0 (footprint <= a0+2)
    float g0 = (1.0f - wy) * (1.0f - f0);
    float g1 = (1.0f - wy) * f0;
    float g2 = wy * (1.0f - f1);
    float g3 = wy * f1;
    float w0 = g0, w1 = 0.0f, w2 = 0.0f;
    if (a1 == a0) w0 += g1; else w1 += g1;
    if (b0 == a0) w0 += g2; else w1 += g2;
    int ob1 = b1 - a0;
    if (ob1 == 0) w0 += g3; else if (ob1 == 1) w1 += g3; else w2 += g3;
    float4 e;
    e.x = w0; e.y = w1; e.z = w2;
    e.w = __int_as_float(a0);        // patch-local base index [0,223]
    return e;
}

__global__ __launch_bounds__(448)
void roi_patch_kernel(const float* __restrict__ x,
                      const int* __restrict__ tops,
                      const int* __restrict__ lefts,
                      const int* __restrict__ crop_hs,
                      const int* __restrict__ crop_ws,
                      float* __restrict__ out,
                      int out_size) {
    __shared__ float  hA[MAXPR][IMG];
    __shared__ float  hB[MAXPR][IMG];
    __shared__ float4 rowE[ROWS];

    const int n   = blockIdx.y;
    const int y0  = blockIdx.x * ROWS;
    const int tid = threadIdx.x;
    const int b   = n >> 2;
    const int gi  = (n >> 1) & 1;
    const int gj  = n & 1;

    const int ch = crop_hs[n], cw = crop_ws[n];
    const int tp = tops[n],    lf = lefts[n];

    // per-thread column entry (col = tid) -- registers
    const float4 ce = make_entry(tid, cw, lf);
    const int ca = __float_as_int(ce.w);
    const int cb = gj * PATCH;
    const int c0 = cb + ca;
    const int c1 = cb + min(ca + 1, 223);
    const int c2 = cb + min(ca + 2, 223);

    if (tid < ROWS) rowE[tid] = make_entry(y0 + tid, ch, tp);

    // patch_indices tail (float values; harness reads flat buffer as f32)
    if (blockIdx.x == 0 && n == 0 && tid < 128) {
        out[(size_t)out_size - 128 + tid] = (float)(tid & 3);
    }

    // block-uniform patch-row range, computed per-thread (no barrier needed
    // before the prologue gathers; rowE itself is consumed only after B1)
    const int pr_min = __float_as_int(make_entry(y0, ch, tp).w);
    const int pr_max = min(__float_as_int(make_entry(y0 + ROWS - 1, ch, tp).w) + 2, 223);
    const int nrows  = pr_max - pr_min + 1;   // <= MAXPR

    const float* xb = x + (size_t)b * 3 * IMG * IMG + (size_t)(gi * PATCH + pr_min) * IMG;
    float* ob = out + (size_t)n * 3 * IMG * IMG + (size_t)y0 * IMG + tid;

    float v0[MAXPR], v1[MAXPR], v2[MAXPR];

    // ---- macro helpers (unrolled, static reg indexing) ----
#define GATHER(CH)                                                        \
    {                                                                     \
        const float* xc = xb + (size_t)(CH) * IMG * IMG;                  \
        _Pragma("unroll")                                                 \
        for (int k = 0; k < MAXPR; ++k) {                                 \
            if (k < nrows) {                                              \
                const float* xr = xc + (size_t)k * IMG;                   \
                v0[k] = xr[c0]; v1[k] = xr[c1]; v2[k] = xr[c2];           \
            }                                                             \
        }                                                                 \
    }

#define HWRITE(BUF)                                                       \
    {                                                                     \
        _Pragma("unroll")                                                 \
        for (int k = 0; k < MAXPR; ++k) {                                 \
            if (k < nrows) {                                              \
                BUF[k][tid] = ce.x * v0[k] + ce.y * v1[k] + ce.z * v2[k]; \
            }                                                             \
        }                                                                 \
    }

#define VPASS(BUF, CH)                                                    \
    {                                                                     \
        float* orow = ob + (size_t)(CH) * IMG * IMG;                      \
        _Pragma("unroll")                                                 \
        for (int r = 0; r < ROWS; ++r) {                                  \
            const float4 re = rowE[r];                                    \
            const int ra = __float_as_int(re.w);                          \
            const int k0 = ra - pr_min;                                   \
            const int k1 = min(ra + 1, 223) - pr_min;                     \
            const int k2 = min(ra + 2, 223) - pr_min;                     \
            *orow = re.x * BUF[k0][tid] + re.y * BUF[k1][tid]             \
                  + re.z * BUF[k2][tid];                                  \
            orow += IMG;                                                  \
        }                                                                 \
    }

    // prologue: channel 0 -> hA
    GATHER(0);
    HWRITE(hA);
    SOFT_BARRIER();          // B1 (also publishes rowE)

    // phase 1: gather ch1 (loads stay in flight) || vpass ch0 ; write hB
    GATHER(1);
    VPASS(hA, 0);
    HWRITE(hB);
    SOFT_BARRIER();          // B2

    // phase 2: gather ch2 || vpass ch1 ; write hA
    GATHER(2);
    VPASS(hB, 1);
    HWRITE(hA);
    SOFT_BARRIER();          // B3

    // epilogue: vpass ch2 (stores drain at kernel end)
    VPASS(hA, 2);

#undef GATHER
#undef HWRITE
#undef VPASS
}

extern "C" void kernel_launch(void* const* d_in, const int* in_sizes, int n_in,
                              void* d_out, int out_size, void* d_ws, size_t ws_size,
                              hipStream_t stream) {
    const float* x        = (const float*)d_in[0];
    const int*   tops     = (const int*)d_in[1];
    const int*   lefts    = (const int*)d_in[2];
    const int*   crop_hs  = (const int*)d_in[3];
    const int*   crop_ws  = (const int*)d_in[4];
    float*       out      = (float*)d_out;

    dim3 grid(IMG / ROWS, 128);   // 56 x 128 blocks
    dim3 block(IMG);              // 448 threads = 7 waves
    roi_patch_kernel<<<grid, block, 0, stream>>>(x, tops, lefts, crop_hs, crop_ws,
                                                 out, out_size);
}